// Round 5
// baseline (208.976 us; speedup 1.0000x reference)
//
#include <hip/hip_runtime.h>
#include <hip/hip_bf16.h>

#define NNODES 50000
#define NFEAT  128
#define NEDGES 600000
#define HID    256
#define HID2   128
#define LEAKY  0.01f

typedef __attribute__((ext_vector_type(8))) short short8;
typedef __attribute__((ext_vector_type(4))) float floatx4;

// Truncation split: x ~= hi + lo (each bf16), residual ~2^-17 rel.
__device__ __forceinline__ void split_bf16(float x, unsigned short& hi, unsigned short& lo) {
  union { float f; unsigned u; } a; a.f = x;
  hi = (unsigned short)(a.u >> 16);
  union { float f; unsigned u; } h; h.u = (unsigned)hi << 16;
  union { float f; unsigned u; } r; r.f = x - h.f;
  lo = (unsigned short)(r.u >> 16);
}

// RNE fp32 -> bf16 (scalar)
__device__ __forceinline__ unsigned short bf16_rne(float x) {
  union { float f; unsigned u; } a; a.f = x;
  unsigned r = a.u + 0x7FFFu + ((a.u >> 16) & 1u);
  return (unsigned short)(r >> 16);
}

// RNE pack two fp32 -> u32 of 2 bf16 (a in low half) — emits cvt_pk.
__device__ __forceinline__ unsigned pack2_rne(float a, float b) {
  __hip_bfloat162 h = __float22bfloat162_rn(make_float2(a, b));
  unsigned u; __builtin_memcpy(&u, &h, 4); return u;
}

__device__ __forceinline__ float ubits2f(unsigned u) {
  union { unsigned u; float f; } c; c.u = u; return c.f;
}

// relu(P+Q) for a packed bf16 pair (b1 pre-folded into P), repacked RNE.
__device__ __forceinline__ unsigned fuse2(unsigned pw, unsigned qw) {
  const float a0 = ubits2f(pw << 16), a1 = ubits2f(pw & 0xFFFF0000u);
  const float c0 = ubits2f(qw << 16), c1 = ubits2f(qw & 0xFFFF0000u);
  return pack2_rne(fmaxf(a0 + c0, 0.f), fmaxf(a1 + c1, 0.f));
}

// ---------------------------------------------------------------------------
// pack_w: merged W2 + W1 packing into MFMA B-frag order, bf16 hi/lo planes.
// W2F[((ks*8+nf)*64+l)*8+i]:  k=ks*32+(l>>4)*8+i, col=nf*16+(l&15)   (32768/plane)
// W1F[((ks*32+nf)*64+l)*8+i]: k=ks*32+(l>>4)*8+i, n=nf*16+(l&15)     (65536/plane)
//   W1'[k][n] = n<256 ? W1[k][n] : W1[128+k][n-256]
// ---------------------------------------------------------------------------
__global__ __launch_bounds__(256) void pack_w(const float* __restrict__ W2,
                                              const float* __restrict__ W1,
                                              unsigned short* __restrict__ W2F,
                                              unsigned short* __restrict__ W1F) {
  const int gid = blockIdx.x * 256 + threadIdx.x;
  if (gid < 32768) {
    const int idx = gid;
    const int i  = idx & 7;
    const int l  = (idx >> 3) & 63;
    const int nf = (idx >> 9) & 7;
    const int ks = idx >> 12;
    const int k   = ks * 32 + (l >> 4) * 8 + i;
    const int col = nf * 16 + (l & 15);
    unsigned short hi, lo;
    split_bf16(W2[k * HID2 + col], hi, lo);
    W2F[idx]         = hi;
    W2F[32768 + idx] = lo;
  } else if (gid < 32768 + 65536) {
    const int idx = gid - 32768;
    const int i  = idx & 7;
    const int l  = (idx >> 3) & 63;
    const int nf = (idx >> 9) & 31;
    const int ks = idx >> 14;
    const int k = ks * 32 + (l >> 4) * 8 + i;
    const int n = nf * 16 + (l & 15);
    const float v = (n < 256) ? W1[k * HID + n] : W1[(128 + k) * HID + (n - 256)];
    unsigned short hi, lo;
    split_bf16(v, hi, lo);
    W1F[idx]         = hi;
    W1F[65536 + idx] = lo;
  }
}

// ---------------------------------------------------------------------------
// pq_mfma: PQb[n][0:512] = bf16_rne( x[n] @ W1' + [b1, 0] )  (b1 folded into
// the P half). 3-term split MFMA. Block: 64 nodes x 256 cols (nhalf).
// ---------------------------------------------------------------------------
__global__ __launch_bounds__(256) void pq_mfma(
    const float* __restrict__ x, const unsigned short* __restrict__ W1F,
    const float* __restrict__ b1, unsigned short* __restrict__ PQb) {
  const int bid   = blockIdx.x;
  const int nhalf = bid & 1;
  const int n0    = (bid >> 1) * 64;
  const int t     = threadIdx.x;

  __shared__ __align__(16) unsigned short xhi[64 * 128];  // 16 KB swizzled
  __shared__ __align__(16) unsigned short xlo[64 * 128];  // 16 KB swizzled

#pragma unroll
  for (int rep = 0; rep < 8; ++rep) {
    const int flat = rep * 1024 + t * 4;
    const int row = flat >> 7, f0 = flat & 127;
    float4 v = make_float4(0.f, 0.f, 0.f, 0.f);
    if (n0 + row < NNODES)
      v = *reinterpret_cast<const float4*>(&x[(size_t)(n0 + row) * NFEAT + f0]);
    unsigned short h[4], l[4];
    split_bf16(v.x, h[0], l[0]); split_bf16(v.y, h[1], l[1]);
    split_bf16(v.z, h[2], l[2]); split_bf16(v.w, h[3], l[3]);
    const unsigned bt = (unsigned)(row * 256) +
                        (((unsigned)(2 * f0)) ^ (((unsigned)(row & 7)) << 4));
    *reinterpret_cast<uint2*>(reinterpret_cast<char*>(xhi) + bt) =
        make_uint2((unsigned)h[0] | ((unsigned)h[1] << 16),
                   (unsigned)h[2] | ((unsigned)h[3] << 16));
    *reinterpret_cast<uint2*>(reinterpret_cast<char*>(xlo) + bt) =
        make_uint2((unsigned)l[0] | ((unsigned)l[1] << 16),
                   (unsigned)l[2] | ((unsigned)l[3] << 16));
  }
  __syncthreads();

  const int wid = t >> 6, lane = t & 63;
  const int rg = wid >> 1, cg = wid & 1;
  const int lr = lane & 15, kc = lane >> 4;

  floatx4 acc[2][8];
#pragma unroll
  for (int mf = 0; mf < 2; ++mf)
#pragma unroll
    for (int nf = 0; nf < 8; ++nf) acc[mf][nf] = (floatx4)0.f;

#pragma unroll
  for (int ks = 0; ks < 4; ++ks) {
    short8 ah[2], al[2];
#pragma unroll
    for (int mf = 0; mf < 2; ++mf) {
      const int row = rg * 32 + mf * 16 + lr;
      const unsigned bt = (unsigned)(row * 256) +
                          (((unsigned)(ks * 64 + kc * 16)) ^ (((unsigned)(row & 7)) << 4));
      ah[mf] = *reinterpret_cast<const short8*>(reinterpret_cast<const char*>(xhi) + bt);
      al[mf] = *reinterpret_cast<const short8*>(reinterpret_cast<const char*>(xlo) + bt);
    }
#pragma unroll
    for (int nf = 0; nf < 8; ++nf) {
      const int nfg = nhalf * 16 + cg * 8 + nf;
      const size_t off = ((size_t)(ks * 32 + nfg) * 64 + lane) * 8;
      const short8 bh = *reinterpret_cast<const short8*>(W1F + off);
      const short8 bl = *reinterpret_cast<const short8*>(W1F + 65536 + off);
#pragma unroll
      for (int mf = 0; mf < 2; ++mf) {
        acc[mf][nf] = __builtin_amdgcn_mfma_f32_16x16x32_bf16(ah[mf], bh, acc[mf][nf], 0, 0, 0);
        acc[mf][nf] = __builtin_amdgcn_mfma_f32_16x16x32_bf16(ah[mf], bl, acc[mf][nf], 0, 0, 0);
        acc[mf][nf] = __builtin_amdgcn_mfma_f32_16x16x32_bf16(al[mf], bh, acc[mf][nf], 0, 0, 0);
      }
    }
  }

  // epilogue: +b1 on the P half (nhalf==0), RNE -> bf16, store.
  float bias[8];
#pragma unroll
  for (int nf = 0; nf < 8; ++nf)
    bias[nf] = (nhalf == 0) ? b1[cg * 128 + nf * 16 + lr] : 0.f;

#pragma unroll
  for (int mf = 0; mf < 2; ++mf)
#pragma unroll
    for (int nf = 0; nf < 8; ++nf)
#pragma unroll
      for (int r = 0; r < 4; ++r) {
        const int node = n0 + rg * 32 + mf * 16 + kc * 4 + r;
        const int col  = nhalf * 256 + cg * 128 + nf * 16 + lr;
        if (node < NNODES)
          PQb[(size_t)node * 512 + col] = bf16_rne(acc[mf][nf][r] + bias[nf]);
      }
}

// ---------------------------------------------------------------------------
// edge_mlp_mfma4: per 64-edge tile, K-split pipelined gather.
//   All 16 uint4 gather loads issued up front; half-0 (cols 0-127) written,
//   barrier, MFMA ks0-3 overlaps half-1 load latency; half-1 written,
//   barrier, MFMA ks4-7; fused epilogue.
// ---------------------------------------------------------------------------
__global__ __launch_bounds__(256) void edge_mlp_mfma4(
    const int* __restrict__ ei,
    const unsigned short* __restrict__ W2F, const float* __restrict__ b2,
    const float* __restrict__ W3, const float* __restrict__ b3,
    const unsigned short* __restrict__ PQb, float* __restrict__ out) {
  const int t  = threadIdx.x;
  const int e0 = blockIdx.x * 64;
  const int wid = t >> 6, lane = t & 63;
  const int q    = lane >> 4;            // quad 0..3: which edge of the iter
  const int vo16 = (lane & 15) * 16;     // byte offset in a 256B half-row

  __shared__ __align__(16) unsigned short h1s[64 * 256];  // 32 KB swizzled
  __shared__ float outs[4][64];

  // lanes 0-15 hold this wave's 16 edge indices (replicated to all quads)
  const int rv = ei[e0 + wid * 16 + (lane & 15)];
  const int cv = ei[NEDGES + e0 + wid * 16 + (lane & 15)];
  const char* PQc = reinterpret_cast<const char*>(PQb);

  // ---- issue all gather loads (4 edges per iteration via quads) ----
  uint4 P0[4], P1[4], Q0[4], Q1[4];
#pragma unroll
  for (int it = 0; it < 4; ++it) {
    const int r = __shfl(rv, 4 * it + q);
    const int c = __shfl(cv, 4 * it + q);
    const char* bp = PQc + (size_t)r * 1024 + vo16;
    const char* bq = PQc + (size_t)c * 1024 + vo16;
    P0[it] = *reinterpret_cast<const uint4*>(bp);        // cols   0-127 (P)
    P1[it] = *reinterpret_cast<const uint4*>(bp + 256);  // cols 128-255 (P)
    Q0[it] = *reinterpret_cast<const uint4*>(bq + 512);  // cols   0-127 (Q)
    Q1[it] = *reinterpret_cast<const uint4*>(bq + 768);  // cols 128-255 (Q)
  }

  // ---- half 0: relu(P+Q) -> swizzled LDS (b128, bank-balanced) ----
#pragma unroll
  for (int it = 0; it < 4; ++it) {
    const uint4 o = make_uint4(fuse2(P0[it].x, Q0[it].x), fuse2(P0[it].y, Q0[it].y),
                               fuse2(P0[it].z, Q0[it].z), fuse2(P0[it].w, Q0[it].w));
    const int e = wid * 16 + 4 * it + q;
    const unsigned bt = (unsigned)(e * 512) +
                        (((unsigned)vo16) ^ (((unsigned)(e & 7)) << 4));
    *reinterpret_cast<uint4*>(reinterpret_cast<char*>(h1s) + bt) = o;
  }
  __syncthreads();

  // ---- MFMA setup: wave w -> cols [32w,32w+32) (2 nf), 64 rows (4 mf) ----
  const int lr = lane & 15, kc = lane >> 4;

  floatx4 acc[4][2];
#pragma unroll
  for (int mf = 0; mf < 4; ++mf)
#pragma unroll
    for (int nf = 0; nf < 2; ++nf) acc[mf][nf] = (floatx4)0.f;

  // ---- MFMA ks 0-3 (cols 0-127) — overlaps half-1 load latency ----
#pragma unroll
  for (int ks = 0; ks < 4; ++ks) {
    short8 ah[4];
#pragma unroll
    for (int mf = 0; mf < 4; ++mf) {
      const int row = mf * 16 + lr;
      const unsigned bt = (unsigned)(row * 512) +
                          (((unsigned)(ks * 64 + kc * 16)) ^ (((unsigned)(row & 7)) << 4));
      ah[mf] = *reinterpret_cast<const short8*>(reinterpret_cast<const char*>(h1s) + bt);
    }
#pragma unroll
    for (int nf = 0; nf < 2; ++nf) {
      const int nfg = wid * 2 + nf;
      const unsigned off = (unsigned)(((ks * 8 + nfg) * 64 + lane) * 8);
      const short8 bh = *reinterpret_cast<const short8*>(W2F + off);
      const short8 bl = *reinterpret_cast<const short8*>(W2F + 32768 + off);
#pragma unroll
      for (int mf = 0; mf < 4; ++mf) {
        acc[mf][nf] = __builtin_amdgcn_mfma_f32_16x16x32_bf16(ah[mf], bh, acc[mf][nf], 0, 0, 0);
        acc[mf][nf] = __builtin_amdgcn_mfma_f32_16x16x32_bf16(ah[mf], bl, acc[mf][nf], 0, 0, 0);
      }
    }
  }

  // ---- half 1: relu(P+Q) -> LDS ----
#pragma unroll
  for (int it = 0; it < 4; ++it) {
    const uint4 o = make_uint4(fuse2(P1[it].x, Q1[it].x), fuse2(P1[it].y, Q1[it].y),
                               fuse2(P1[it].z, Q1[it].z), fuse2(P1[it].w, Q1[it].w));
    const int e = wid * 16 + 4 * it + q;
    const unsigned bt = (unsigned)(e * 512) +
                        (((unsigned)(256 + vo16)) ^ (((unsigned)(e & 7)) << 4));
    *reinterpret_cast<uint4*>(reinterpret_cast<char*>(h1s) + bt) = o;
  }
  __syncthreads();

  // ---- MFMA ks 4-7 (cols 128-255) ----
#pragma unroll
  for (int ks = 4; ks < 8; ++ks) {
    short8 ah[4];
#pragma unroll
    for (int mf = 0; mf < 4; ++mf) {
      const int row = mf * 16 + lr;
      const unsigned bt = (unsigned)(row * 512) +
                          (((unsigned)(ks * 64 + kc * 16)) ^ (((unsigned)(row & 7)) << 4));
      ah[mf] = *reinterpret_cast<const short8*>(reinterpret_cast<const char*>(h1s) + bt);
    }
#pragma unroll
    for (int nf = 0; nf < 2; ++nf) {
      const int nfg = wid * 2 + nf;
      const unsigned off = (unsigned)(((ks * 8 + nfg) * 64 + lane) * 8);
      const short8 bh = *reinterpret_cast<const short8*>(W2F + off);
      const short8 bl = *reinterpret_cast<const short8*>(W2F + 32768 + off);
#pragma unroll
      for (int mf = 0; mf < 4; ++mf) {
        acc[mf][nf] = __builtin_amdgcn_mfma_f32_16x16x32_bf16(ah[mf], bh, acc[mf][nf], 0, 0, 0);
        acc[mf][nf] = __builtin_amdgcn_mfma_f32_16x16x32_bf16(ah[mf], bl, acc[mf][nf], 0, 0, 0);
      }
    }
  }

  // ---- epilogue: leaky_relu(C+b2) @ W3, reduce over 16 col-lanes ----
  float w3v[2], b2v[2];
#pragma unroll
  for (int nf = 0; nf < 2; ++nf) {
    const int col = wid * 32 + nf * 16 + lr;
    w3v[nf] = W3[col];
    b2v[nf] = b2[col];
  }

  float part[4][4];
#pragma unroll
  for (int mf = 0; mf < 4; ++mf)
#pragma unroll
    for (int r = 0; r < 4; ++r) {
      float s = 0.f;
#pragma unroll
      for (int nf = 0; nf < 2; ++nf) {
        float h = acc[mf][nf][r] + b2v[nf];
        h = (h > 0.f) ? h : LEAKY * h;
        s = fmaf(h, w3v[nf], s);
      }
      part[mf][r] = s;
    }

#pragma unroll
  for (int m = 1; m <= 8; m <<= 1)
#pragma unroll
    for (int mf = 0; mf < 4; ++mf)
#pragma unroll
      for (int r = 0; r < 4; ++r) part[mf][r] += __shfl_xor(part[mf][r], m, 64);

  if (lr == 0) {
#pragma unroll
    for (int mf = 0; mf < 4; ++mf)
#pragma unroll
      for (int r = 0; r < 4; ++r) outs[wid][mf * 16 + kc * 4 + r] = part[mf][r];
  }
  __syncthreads();

  if (t < 64) {
    out[e0 + t] = outs[0][t] + outs[1][t] + outs[2][t] + outs[3][t] + b3[0];
  }
}

// ---------------------------------------------------------------------------
// Fallback (ws too small): direct fp32 path, 32-edge tiles.
// ---------------------------------------------------------------------------
__global__ __launch_bounds__(256) void edge_mlp_direct(
    const float* __restrict__ x, const int* __restrict__ ei,
    const float* __restrict__ W1, const float* __restrict__ b1,
    const float* __restrict__ W2, const float* __restrict__ b2,
    const float* __restrict__ W3, const float* __restrict__ b3,
    float* __restrict__ out) {
  const int t  = threadIdx.x;
  const int e0 = blockIdx.x * 32;

  __shared__ __align__(16) float h1f[32 * HID];
  __shared__ int eidx[2][32];

  if (t < 32)      eidx[0][t]      = ei[e0 + t];
  else if (t < 64) eidx[1][t - 32] = ei[NEDGES + e0 + (t - 32)];
  __syncthreads();

  const float b1r = b1[t];
  __shared__ float xr[32][128];
  __shared__ float xc[32][128];
  for (int idx = t; idx < 32 * 128; idx += 256) {
    const int e = idx >> 7, f = idx & 127;
    xr[e][f] = x[(size_t)eidx[0][e] * NFEAT + f];
    xc[e][f] = x[(size_t)eidx[1][e] * NFEAT + f];
  }
  __syncthreads();
  float s[32];
#pragma unroll
  for (int e = 0; e < 32; ++e) s[e] = b1r;
  for (int f = 0; f < 128; ++f) {
    const float wr = W1[f * HID + t];
    const float wb = W1[(128 + f) * HID + t];
#pragma unroll
    for (int e = 0; e < 32; ++e)
      s[e] = fmaf(xr[e][f], wr, fmaf(xc[e][f], wb, s[e]));
  }
#pragma unroll
  for (int e = 0; e < 32; ++e) h1f[e * HID + t] = fmaxf(s[e], 0.f);
  __syncthreads();

  const int tr = t >> 5;
  const int tc = t & 31;
  float acc[4][4];
#pragma unroll
  for (int i = 0; i < 4; ++i)
#pragma unroll
    for (int j = 0; j < 4; ++j) acc[i][j] = 0.f;

  const float4* __restrict__ W2v = reinterpret_cast<const float4*>(W2);
  const float4* __restrict__ h1v = reinterpret_cast<const float4*>(h1f);
  for (int k = 0; k < HID; k += 4) {
    float4 a[4];
#pragma unroll
    for (int i = 0; i < 4; ++i) a[i] = h1v[((4 * tr + i) * HID + k) >> 2];
    float4 b[4];
#pragma unroll
    for (int kk = 0; kk < 4; ++kk) b[kk] = W2v[(k + kk) * 32 + tc];
#pragma unroll
    for (int i = 0; i < 4; ++i) {
      const float* av = reinterpret_cast<const float*>(&a[i]);
#pragma unroll
      for (int kk = 0; kk < 4; ++kk) {
        const float* bv = reinterpret_cast<const float*>(&b[kk]);
#pragma unroll
        for (int j = 0; j < 4; ++j) acc[i][j] = fmaf(av[kk], bv[j], acc[i][j]);
      }
    }
  }

  float w3r[4], b2r[4];
#pragma unroll
  for (int j = 0; j < 4; ++j) {
    w3r[j] = W3[4 * tc + j];
    b2r[j] = b2[4 * tc + j];
  }
  const float b3v = b3[0];
  float partial[4];
#pragma unroll
  for (int i = 0; i < 4; ++i) {
    float sp = 0.f;
#pragma unroll
    for (int j = 0; j < 4; ++j) {
      float h = acc[i][j] + b2r[j];
      h = (h > 0.f) ? h : LEAKY * h;
      sp = fmaf(h, w3r[j], sp);
    }
    partial[i] = sp;
  }
#pragma unroll
  for (int m = 16; m >= 1; m >>= 1)
#pragma unroll
    for (int i = 0; i < 4; ++i) partial[i] += __shfl_xor(partial[i], m, 32);
  if (tc == 0) {
#pragma unroll
    for (int i = 0; i < 4; ++i) out[e0 + 4 * tr + i] = partial[i] + b3v;
  }
}

extern "C" void kernel_launch(void* const* d_in, const int* in_sizes, int n_in,
                              void* d_out, int out_size, void* d_ws, size_t ws_size,
                              hipStream_t stream) {
  const float* x  = (const float*)d_in[0];
  const int*   ei = (const int*)d_in[1];
  const float* W1 = (const float*)d_in[2];
  const float* b1 = (const float*)d_in[3];
  const float* W2 = (const float*)d_in[4];
  const float* b2 = (const float*)d_in[5];
  const float* W3 = (const float*)d_in[6];
  const float* b3 = (const float*)d_in[7];
  float* out = (float*)d_out;

  const size_t pqb_bytes = (size_t)NNODES * 512 * 2;      // 51,200,000
  const size_t w2f_bytes = (size_t)2 * 32768 * 2;         // 131,072
  const size_t w1f_bytes = (size_t)2 * 65536 * 2;         // 262,144
  const size_t need = pqb_bytes + w2f_bytes + w1f_bytes;

  if (ws_size >= need) {
    unsigned short* PQb = (unsigned short*)d_ws;
    unsigned short* W2F = (unsigned short*)((char*)d_ws + pqb_bytes);
    unsigned short* W1F = (unsigned short*)((char*)d_ws + pqb_bytes + w2f_bytes);

    pack_w<<<(32768 + 65536 + 255) / 256, 256, 0, stream>>>(W2, W1, W2F, W1F);
    const int pq_blocks = ((NNODES + 63) / 64) * 2;       // 1564
    pq_mfma<<<pq_blocks, 256, 0, stream>>>(x, W1F, b1, PQb);
    edge_mlp_mfma4<<<NEDGES / 64, 256, 0, stream>>>(ei, W2F, b2, W3, b3, PQb, out);
  } else {
    edge_mlp_direct<<<NEDGES / 32, 256, 0, stream>>>(x, ei, W1, b1, W2, b2, W3, b3, out);
  }
}